// Round 1
// baseline (3414.630 us; speedup 1.0000x reference)
//
#include <hip/hip_runtime.h>
#include <hip/hip_bf16.h>

// Qwen3 attention block, fp32-exact round-0 implementation.
// B=1, S=2048, HIDDEN=4096, NQ=32, NKV=8 (GQA R=4), HD=128.
// Pipeline: gemm_f32(qkv) -> rmsnorm_rope (in-place) -> flash_attn -> gemm_f32(out).

#define S_LEN   2048
#define HIDDEN  4096
#define NQ      32
#define NKV     8
#define HD      128
#define QKV_DIM 6144      // (NQ + 2*NKV) * HD
#define NQHD    4096      // NQ * HD
#define K_OFF   4096      // NQ*HD
#define V_OFF   5120      // (NQ+NKV)*HD
#define EPSF    1e-6f

// ---------------------------------------------------------------------------
// Tiled fp32 GEMM: C[M,N] = A[M,K] @ B[K,N], all row-major, dims % 128 == 0.
// 128x128 tile, BK=16, 256 threads, 8x8 per thread (split 4+4 to break bank
// conflicts: thread's rows {ty*4..+3, 64+ty*4..+3}, cols likewise).
// ---------------------------------------------------------------------------
#define GBM 128
#define GBN 128
#define GBK 16

__global__ __launch_bounds__(256) void gemm_f32(const float* __restrict__ A,
                                                const float* __restrict__ B,
                                                float* __restrict__ C,
                                                int M, int N, int K) {
    __shared__ float As[GBK][GBM + 4];  // stored transposed [k][m], +4 pad
    __shared__ float Bs[GBK][GBN];

    const int tid = threadIdx.x;
    const int tx = tid & 15, ty = tid >> 4;
    const int m0 = blockIdx.y * GBM, n0 = blockIdx.x * GBN;

    // A staging: each thread 2x float4 along K; rows lr and 64+lr
    const int lr = tid >> 2;            // 0..63
    const int lk = (tid & 3) * 4;       // 0,4,8,12
    // B staging: rows br and 8+br, 128 floats per row
    const int brr = tid >> 5;           // 0..7
    const int bcc = (tid & 31) * 4;     // 0..124

    float accf[8][8] = {};

    for (int k0 = 0; k0 < K; k0 += GBK) {
        float4 a0 = *(const float4*)(A + (size_t)(m0 + lr) * K + k0 + lk);
        float4 a1 = *(const float4*)(A + (size_t)(m0 + 64 + lr) * K + k0 + lk);
        float4 b0 = *(const float4*)(B + (size_t)(k0 + brr) * N + n0 + bcc);
        float4 b1 = *(const float4*)(B + (size_t)(k0 + 8 + brr) * N + n0 + bcc);
        __syncthreads();  // previous iteration's compute done reading LDS
        As[lk + 0][lr] = a0.x; As[lk + 1][lr] = a0.y;
        As[lk + 2][lr] = a0.z; As[lk + 3][lr] = a0.w;
        As[lk + 0][64 + lr] = a1.x; As[lk + 1][64 + lr] = a1.y;
        As[lk + 2][64 + lr] = a1.z; As[lk + 3][64 + lr] = a1.w;
        *(float4*)&Bs[brr][bcc] = b0;
        *(float4*)&Bs[8 + brr][bcc] = b1;
        __syncthreads();

        #pragma unroll
        for (int k = 0; k < GBK; ++k) {
            float4 aA = *(const float4*)&As[k][ty * 4];
            float4 aB = *(const float4*)&As[k][64 + ty * 4];
            float4 bA = *(const float4*)&Bs[k][tx * 4];
            float4 bB = *(const float4*)&Bs[k][64 + tx * 4];
            float ar[8] = {aA.x, aA.y, aA.z, aA.w, aB.x, aB.y, aB.z, aB.w};
            float bc[8] = {bA.x, bA.y, bA.z, bA.w, bB.x, bB.y, bB.z, bB.w};
            #pragma unroll
            for (int i = 0; i < 8; ++i)
                #pragma unroll
                for (int j = 0; j < 8; ++j)
                    accf[i][j] += ar[i] * bc[j];
        }
    }

    #pragma unroll
    for (int i = 0; i < 8; ++i) {
        int row = m0 + ((i < 4) ? (ty * 4 + i) : (64 + ty * 4 + (i - 4)));
        float4 c0 = make_float4(accf[i][0], accf[i][1], accf[i][2], accf[i][3]);
        float4 c1 = make_float4(accf[i][4], accf[i][5], accf[i][6], accf[i][7]);
        *(float4*)(C + (size_t)row * N + n0 + tx * 4) = c0;
        *(float4*)(C + (size_t)row * N + n0 + 64 + tx * 4) = c1;
    }
}

// ---------------------------------------------------------------------------
// Fused RMSNorm + RoPE, in-place on the qkv buffer.
// One block (128 threads) per (s, head); heads 0..31 = q, 32..39 = k.
// RoPE mixes only d and d+64 within the same head, so in-place is safe.
// ---------------------------------------------------------------------------
__global__ __launch_bounds__(128) void rmsnorm_rope(float* __restrict__ qkv,
                                                    const float* __restrict__ qg,
                                                    const float* __restrict__ kg,
                                                    const float* __restrict__ cosb,
                                                    const float* __restrict__ sinb) {
    const int h = blockIdx.x;   // 0..39
    const int s = blockIdx.y;   // 0..2047
    const int d = threadIdx.x;  // 0..127
    const bool isq = (h < NQ);
    const int off = isq ? h * HD : K_OFF + (h - NQ) * HD;
    float* base = qkv + (size_t)s * QKV_DIM + off;

    float x = base[d];
    float ss = x * x;
    #pragma unroll
    for (int o = 32; o; o >>= 1) ss += __shfl_xor(ss, o);

    __shared__ float red[2];
    __shared__ float sh[HD];
    if ((d & 63) == 0) red[d >> 6] = ss;
    __syncthreads();
    float tot = red[0] + red[1];
    float rms = rsqrtf(tot * (1.0f / (float)HD) + EPSF);
    const float* gamma = isq ? qg : kg;
    float xn = x * rms * gamma[d];
    sh[d] = xn;
    __syncthreads();

    float out;
    if (d < 64) {
        float c = cosb[s * 64 + d], sn = sinb[s * 64 + d];
        out = xn * c - sh[d + 64] * sn;
    } else {
        int j = d - 64;
        float c = cosb[s * 64 + j], sn = sinb[s * 64 + j];
        out = xn * c + sh[d - 64] * sn;
    }
    base[d] = out;
}

// ---------------------------------------------------------------------------
// Flash-style causal GQA attention, fp32, online softmax.
// Block = 256 threads handles one (q-tile of 32 rows, q-head). K/V tiles of
// 64 rows iterated up to the diagonal. K and V share one LDS buffer
// (K consumed by score phase before V overwrite). attn layout [s][h*HD+d].
// ---------------------------------------------------------------------------
#define FBM 32
#define FBN 64

__global__ __launch_bounds__(256) void flash_attn(const float* __restrict__ qkv,
                                                  float* __restrict__ attn) {
    __shared__ float Qs[FBM][132];
    __shared__ float KVs[FBN][132];
    __shared__ float Ss[FBM][68];
    __shared__ float m_i[FBM], l_i[FBM], al[FBM];

    const int qt = blockIdx.x, h = blockIdx.y;
    const int kvh = h >> 2;              // GQA: 4 q heads per kv head
    const int m0 = qt * FBM;
    const int tid = threadIdx.x;

    // load Q tile: 32 rows x 128
    #pragma unroll
    for (int l = 0; l < 4; ++l) {
        int f = tid + l * 256;
        int r = f >> 5, c4 = (f & 31) * 4;
        *(float4*)&Qs[r][c4] =
            *(const float4*)(qkv + (size_t)(m0 + r) * QKV_DIM + h * HD + c4);
    }
    if (tid < FBM) { m_i[tid] = -3e38f; l_i[tid] = 0.f; }

    float4 acc[4] = {};                  // 16 output dims per thread
    const int rg = tid >> 4, cg = tid & 15;   // score phase: rows rg*2..+1, cols cg+16j
    const int rr0 = rg * 2;
    const int pr = tid >> 3, pc4 = tid & 7;   // PV phase: row pr, dims 32*i + pc4*4
    const float scale = 0.08838834764831845f; // HD^-0.5

    const int ntiles = (m0 + FBM - 1) / FBN + 1;
    for (int t = 0; t < ntiles; ++t) {
        const int n0 = t * FBN;
        __syncthreads();  // previous PV done with KVs/Ss

        // load K tile: 64 rows x 128
        #pragma unroll
        for (int l = 0; l < 8; ++l) {
            int f = tid + l * 256;
            int r = f >> 5, c4 = (f & 31) * 4;
            *(float4*)&KVs[r][c4] =
                *(const float4*)(qkv + (size_t)(n0 + r) * QKV_DIM + K_OFF + kvh * HD + c4);
        }
        __syncthreads();

        // scores: each thread 2 rows x 4 (strided) cols
        float sc[2][4] = {{0, 0, 0, 0}, {0, 0, 0, 0}};
        #pragma unroll 8
        for (int k = 0; k < HD; k += 4) {
            float4 q0 = *(const float4*)&Qs[rr0][k];
            float4 q1 = *(const float4*)&Qs[rr0 + 1][k];
            #pragma unroll
            for (int j = 0; j < 4; ++j) {
                float4 kv = *(const float4*)&KVs[cg + 16 * j][k];
                sc[0][j] += q0.x * kv.x + q0.y * kv.y + q0.z * kv.z + q0.w * kv.w;
                sc[1][j] += q1.x * kv.x + q1.y * kv.y + q1.z * kv.z + q1.w * kv.w;
            }
        }

        // online softmax per row (16 lanes per row via shfl_xor reductions)
        #pragma unroll
        for (int i = 0; i < 2; ++i) {
            const int rr = rr0 + i;
            const int qr = m0 + rr;
            float mo = m_i[rr];
            float mp = -3e38f;
            #pragma unroll
            for (int j = 0; j < 4; ++j) {
                float v = sc[i][j] * scale;
                v = (n0 + cg + 16 * j <= qr) ? v : -3e38f;  // causal mask
                sc[i][j] = v;
                mp = fmaxf(mp, v);
            }
            #pragma unroll
            for (int o = 8; o; o >>= 1) mp = fmaxf(mp, __shfl_xor(mp, o));
            float nm = fmaxf(mo, mp);
            float lp = 0.f;
            #pragma unroll
            for (int j = 0; j < 4; ++j) {
                float p = (sc[i][j] > -1e37f) ? __expf(sc[i][j] - nm) : 0.f;
                Ss[rr][cg + 16 * j] = p;
                lp += p;
            }
            #pragma unroll
            for (int o = 8; o; o >>= 1) lp += __shfl_xor(lp, o);
            if (cg == 0) {
                float a = __expf(mo - nm);
                m_i[rr] = nm;
                l_i[rr] = l_i[rr] * a + lp;
                al[rr] = a;
            }
        }
        __syncthreads();  // Ss/al visible; score phase done reading KVs

        // rescale accumulator
        float a_r = al[pr];
        #pragma unroll
        for (int i = 0; i < 4; ++i) {
            acc[i].x *= a_r; acc[i].y *= a_r; acc[i].z *= a_r; acc[i].w *= a_r;
        }

        // load V tile over K
        #pragma unroll
        for (int l = 0; l < 8; ++l) {
            int f = tid + l * 256;
            int r = f >> 5, c4 = (f & 31) * 4;
            *(float4*)&KVs[r][c4] =
                *(const float4*)(qkv + (size_t)(n0 + r) * QKV_DIM + V_OFF + kvh * HD + c4);
        }
        __syncthreads();

        // PV accumulate: acc[r][d] += P[r][j] * V[j][d]
        for (int j = 0; j < FBN; ++j) {
            float p = Ss[pr][j];
            #pragma unroll
            for (int i = 0; i < 4; ++i) {
                float4 v = *(const float4*)&KVs[j][i * 32 + pc4 * 4];
                acc[i].x += p * v.x; acc[i].y += p * v.y;
                acc[i].z += p * v.z; acc[i].w += p * v.w;
            }
        }
    }

    const float linv = 1.0f / l_i[pr];
    #pragma unroll
    for (int i = 0; i < 4; ++i) {
        float4 o = acc[i];
        o.x *= linv; o.y *= linv; o.z *= linv; o.w *= linv;
        *(float4*)(attn + (size_t)(m0 + pr) * NQHD + h * HD + i * 32 + pc4 * 4) = o;
    }
}

// ---------------------------------------------------------------------------
extern "C" void kernel_launch(void* const* d_in, const int* in_sizes, int n_in,
                              void* d_out, int out_size, void* d_ws, size_t ws_size,
                              hipStream_t stream) {
    // inputs (setup_inputs order): positions, hidden_states, Wqkv, Wo,
    //                              q_gamma, k_gamma, cos, sin
    const float* hidden = (const float*)d_in[1];
    const float* Wqkv   = (const float*)d_in[2];
    const float* Wo     = (const float*)d_in[3];
    const float* qg     = (const float*)d_in[4];
    const float* kg     = (const float*)d_in[5];
    const float* cosb   = (const float*)d_in[6];
    const float* sinb   = (const float*)d_in[7];
    float* out = (float*)d_out;

    float* qkv  = (float*)d_ws;                         // 2048*6144 f32 = 50.3 MB
    float* attn = qkv + (size_t)S_LEN * QKV_DIM;        // 2048*4096 f32 = 33.6 MB

    // 1) qkv = hidden @ Wqkv
    gemm_f32<<<dim3(QKV_DIM / GBN, S_LEN / GBM), 256, 0, stream>>>(
        hidden, Wqkv, qkv, S_LEN, QKV_DIM, HIDDEN);

    // 2) RMSNorm + RoPE on q,k heads, in place
    rmsnorm_rope<<<dim3(NQ + NKV, S_LEN), 128, 0, stream>>>(qkv, qg, kg, cosb, sinb);

    // 3) causal GQA flash attention -> attn [s][h*HD+d]
    flash_attn<<<dim3(S_LEN / FBM, NQ), 256, 0, stream>>>(qkv, attn);

    // 4) out = attn @ Wo
    gemm_f32<<<dim3(HIDDEN / GBN, S_LEN / GBM), 256, 0, stream>>>(
        attn, Wo, out, S_LEN, HIDDEN, NQHD);
}

// Round 2
// 1901.580 us; speedup vs baseline: 1.7957x; 1.7957x over previous
//
#include <hip/hip_runtime.h>
#include <hip/hip_bf16.h>

// Qwen3 attention block. Round 2: qkv/out GEMMs -> fp16 MFMA (on-the-fly
// fp32->fp16 conversion in LDS staging, fp32 accumulation).
// B=1, S=2048, HIDDEN=4096, NQ=32, NKV=8 (GQA R=4), HD=128.
// Pipeline: gemm_f16_mfma(qkv) -> rmsnorm_rope (in-place) -> flash_attn(fp32)
//           -> gemm_f16_mfma(out).

#define S_LEN   2048
#define HIDDEN  4096
#define NQ      32
#define NKV     8
#define HD      128
#define QKV_DIM 6144      // (NQ + 2*NKV) * HD
#define NQHD    4096      // NQ * HD
#define K_OFF   4096      // NQ*HD
#define V_OFF   5120      // (NQ+NKV)*HD
#define EPSF    1e-6f

typedef _Float16 half8 __attribute__((ext_vector_type(8)));
typedef _Float16 half4v __attribute__((ext_vector_type(4)));
typedef float floatx4 __attribute__((ext_vector_type(4)));

// ---------------------------------------------------------------------------
// fp16 MFMA GEMM: C[M,N] = A[M,K] @ B[K,N] (row-major fp32 in/out).
// 128x128 tile, BK=32. 4 waves in 2x2, each computes 64x64 via 4x4 MFMA tiles
// of v_mfma_f32_16x16x32_f16. A/B converted fp32->fp16 during LDS staging.
// LDS stride 40 fp16 (80 B): ds_read_b128 fragment reads 16B-aligned and
// conflict-free (stride 20 words spreads 16 lanes' bank quads evenly).
// ---------------------------------------------------------------------------
#define TM 128
#define TN 128
#define TK 32
#define LDH 40

__global__ __launch_bounds__(256) void gemm_f16_mfma(const float* __restrict__ A,
                                                     const float* __restrict__ B,
                                                     float* __restrict__ C,
                                                     int M, int N, int K) {
    __shared__ _Float16 As[TM][LDH];   // [m][k] row-major
    __shared__ _Float16 Bs[TN][LDH];   // [n][k] transposed

    const int tid = threadIdx.x;
    const int m0 = blockIdx.y * TM, n0 = blockIdx.x * TN;
    const int lane = tid & 63;
    const int wave = tid >> 6;
    const int wm = (wave >> 1) * 64, wn = (wave & 1) * 64;
    const int fl = lane & 15, quad = lane >> 4;

    // A staging: thread -> row ar+32l, k-chunk ak..ak+3 (float4, coalesced)
    const int ar = tid >> 3;            // 0..31
    const int ak = (tid & 7) * 4;       // 0,4,..,28
    // B staging: thread -> column n0+bn, k = bk0 + 8l + j (dword column loads,
    // coalesced across the 64 consecutive-bn lanes of each wave)
    const int bn = tid & 127;           // 0..127
    const int bk0 = (tid >> 7) * 4;     // 0 or 4

    floatx4 acc[4][4] = {};

    for (int k0 = 0; k0 < K; k0 += TK) {
        // global loads first (overlap with the barrier)
        float4 av[4];
        #pragma unroll
        for (int l = 0; l < 4; ++l)
            av[l] = *(const float4*)(A + (size_t)(m0 + ar + l * 32) * K + k0 + ak);
        float bv[4][4];
        #pragma unroll
        for (int l = 0; l < 4; ++l) {
            const int kk = k0 + bk0 + l * 8;
            #pragma unroll
            for (int j = 0; j < 4; ++j)
                bv[l][j] = B[(size_t)(kk + j) * N + n0 + bn];
        }

        __syncthreads();   // previous iteration's fragment reads done

        #pragma unroll
        for (int l = 0; l < 4; ++l) {
            half4v h;
            h[0] = (_Float16)av[l].x; h[1] = (_Float16)av[l].y;
            h[2] = (_Float16)av[l].z; h[3] = (_Float16)av[l].w;
            *(half4v*)&As[ar + l * 32][ak] = h;   // 8B store, aligned (80B rows)
        }
        #pragma unroll
        for (int l = 0; l < 4; ++l) {
            half4v h;
            h[0] = (_Float16)bv[l][0]; h[1] = (_Float16)bv[l][1];
            h[2] = (_Float16)bv[l][2]; h[3] = (_Float16)bv[l][3];
            *(half4v*)&Bs[bn][bk0 + l * 8] = h;
        }

        __syncthreads();

        // fragments: A[m=fl][k=quad*8..+7], B[n=fl][k=quad*8..+7]
        half8 af[4], bf[4];
        #pragma unroll
        for (int t = 0; t < 4; ++t) {
            af[t] = *(const half8*)&As[wm + t * 16 + fl][quad * 8];
            bf[t] = *(const half8*)&Bs[wn + t * 16 + fl][quad * 8];
        }
        #pragma unroll
        for (int i = 0; i < 4; ++i)
            #pragma unroll
            for (int j = 0; j < 4; ++j)
                acc[i][j] = __builtin_amdgcn_mfma_f32_16x16x32_f16(
                    af[i], bf[j], acc[i][j], 0, 0, 0);
    }

    // C/D layout: col = lane&15, row = quad*4 + r
    #pragma unroll
    for (int i = 0; i < 4; ++i) {
        #pragma unroll
        for (int j = 0; j < 4; ++j) {
            #pragma unroll
            for (int r = 0; r < 4; ++r) {
                C[(size_t)(m0 + wm + i * 16 + quad * 4 + r) * N
                  + n0 + wn + j * 16 + fl] = acc[i][j][r];
            }
        }
    }
}

// ---------------------------------------------------------------------------
// Fused RMSNorm + RoPE, in-place on the qkv buffer. (unchanged from round 1)
// ---------------------------------------------------------------------------
__global__ __launch_bounds__(128) void rmsnorm_rope(float* __restrict__ qkv,
                                                    const float* __restrict__ qg,
                                                    const float* __restrict__ kg,
                                                    const float* __restrict__ cosb,
                                                    const float* __restrict__ sinb) {
    const int h = blockIdx.x;   // 0..39
    const int s = blockIdx.y;   // 0..2047
    const int d = threadIdx.x;  // 0..127
    const bool isq = (h < NQ);
    const int off = isq ? h * HD : K_OFF + (h - NQ) * HD;
    float* base = qkv + (size_t)s * QKV_DIM + off;

    float x = base[d];
    float ss = x * x;
    #pragma unroll
    for (int o = 32; o; o >>= 1) ss += __shfl_xor(ss, o);

    __shared__ float red[2];
    __shared__ float sh[HD];
    if ((d & 63) == 0) red[d >> 6] = ss;
    __syncthreads();
    float tot = red[0] + red[1];
    float rms = rsqrtf(tot * (1.0f / (float)HD) + EPSF);
    const float* gamma = isq ? qg : kg;
    float xn = x * rms * gamma[d];
    sh[d] = xn;
    __syncthreads();

    float out;
    if (d < 64) {
        float c = cosb[s * 64 + d], sn = sinb[s * 64 + d];
        out = xn * c - sh[d + 64] * sn;
    } else {
        int j = d - 64;
        float c = cosb[s * 64 + j], sn = sinb[s * 64 + j];
        out = xn * c + sh[d - 64] * sn;
    }
    base[d] = out;
}

// ---------------------------------------------------------------------------
// Flash-style causal GQA attention, fp32, online softmax. (unchanged; round-3
// target for fp16 MFMA rewrite pending this round's absmax signal)
// ---------------------------------------------------------------------------
#define FBM 32
#define FBN 64

__global__ __launch_bounds__(256) void flash_attn(const float* __restrict__ qkv,
                                                  float* __restrict__ attn) {
    __shared__ float Qs[FBM][132];
    __shared__ float KVs[FBN][132];
    __shared__ float Ss[FBM][68];
    __shared__ float m_i[FBM], l_i[FBM], al[FBM];

    const int qt = blockIdx.x, h = blockIdx.y;
    const int kvh = h >> 2;              // GQA: 4 q heads per kv head
    const int m0 = qt * FBM;
    const int tid = threadIdx.x;

    #pragma unroll
    for (int l = 0; l < 4; ++l) {
        int f = tid + l * 256;
        int r = f >> 5, c4 = (f & 31) * 4;
        *(float4*)&Qs[r][c4] =
            *(const float4*)(qkv + (size_t)(m0 + r) * QKV_DIM + h * HD + c4);
    }
    if (tid < FBM) { m_i[tid] = -3e38f; l_i[tid] = 0.f; }

    float4 acc[4] = {};
    const int rg = tid >> 4, cg = tid & 15;
    const int rr0 = rg * 2;
    const int pr = tid >> 3, pc4 = tid & 7;
    const float scale = 0.08838834764831845f; // HD^-0.5

    const int ntiles = (m0 + FBM - 1) / FBN + 1;
    for (int t = 0; t < ntiles; ++t) {
        const int n0 = t * FBN;
        __syncthreads();

        #pragma unroll
        for (int l = 0; l < 8; ++l) {
            int f = tid + l * 256;
            int r = f >> 5, c4 = (f & 31) * 4;
            *(float4*)&KVs[r][c4] =
                *(const float4*)(qkv + (size_t)(n0 + r) * QKV_DIM + K_OFF + kvh * HD + c4);
        }
        __syncthreads();

        float sc[2][4] = {{0, 0, 0, 0}, {0, 0, 0, 0}};
        #pragma unroll 8
        for (int k = 0; k < HD; k += 4) {
            float4 q0 = *(const float4*)&Qs[rr0][k];
            float4 q1 = *(const float4*)&Qs[rr0 + 1][k];
            #pragma unroll
            for (int j = 0; j < 4; ++j) {
                float4 kv = *(const float4*)&KVs[cg + 16 * j][k];
                sc[0][j] += q0.x * kv.x + q0.y * kv.y + q0.z * kv.z + q0.w * kv.w;
                sc[1][j] += q1.x * kv.x + q1.y * kv.y + q1.z * kv.z + q1.w * kv.w;
            }
        }

        #pragma unroll
        for (int i = 0; i < 2; ++i) {
            const int rr = rr0 + i;
            const int qr = m0 + rr;
            float mo = m_i[rr];
            float mp = -3e38f;
            #pragma unroll
            for (int j = 0; j < 4; ++j) {
                float v = sc[i][j] * scale;
                v = (n0 + cg + 16 * j <= qr) ? v : -3e38f;
                sc[i][j] = v;
                mp = fmaxf(mp, v);
            }
            #pragma unroll
            for (int o = 8; o; o >>= 1) mp = fmaxf(mp, __shfl_xor(mp, o));
            float nm = fmaxf(mo, mp);
            float lp = 0.f;
            #pragma unroll
            for (int j = 0; j < 4; ++j) {
                float p = (sc[i][j] > -1e37f) ? __expf(sc[i][j] - nm) : 0.f;
                Ss[rr][cg + 16 * j] = p;
                lp += p;
            }
            #pragma unroll
            for (int o = 8; o; o >>= 1) lp += __shfl_xor(lp, o);
            if (cg == 0) {
                float a = __expf(mo - nm);
                m_i[rr] = nm;
                l_i[rr] = l_i[rr] * a + lp;
                al[rr] = a;
            }
        }
        __syncthreads();

        float a_r = al[pr];
        #pragma unroll
        for (int i = 0; i < 4; ++i) {
            acc[i].x *= a_r; acc[i].y *= a_r; acc[i].z *= a_r; acc[i].w *= a_r;
        }

        #pragma unroll
        for (int l = 0; l < 8; ++l) {
            int f = tid + l * 256;
            int r = f >> 5, c4 = (f & 31) * 4;
            *(float4*)&KVs[r][c4] =
                *(const float4*)(qkv + (size_t)(n0 + r) * QKV_DIM + V_OFF + kvh * HD + c4);
        }
        __syncthreads();

        for (int j = 0; j < FBN; ++j) {
            float p = Ss[pr][j];
            #pragma unroll
            for (int i = 0; i < 4; ++i) {
                float4 v = *(const float4*)&KVs[j][i * 32 + pc4 * 4];
                acc[i].x += p * v.x; acc[i].y += p * v.y;
                acc[i].z += p * v.z; acc[i].w += p * v.w;
            }
        }
    }

    const float linv = 1.0f / l_i[pr];
    #pragma unroll
    for (int i = 0; i < 4; ++i) {
        float4 o = acc[i];
        o.x *= linv; o.y *= linv; o.z *= linv; o.w *= linv;
        *(float4*)(attn + (size_t)(m0 + pr) * NQHD + h * HD + i * 32 + pc4 * 4) = o;
    }
}

// ---------------------------------------------------------------------------
extern "C" void kernel_launch(void* const* d_in, const int* in_sizes, int n_in,
                              void* d_out, int out_size, void* d_ws, size_t ws_size,
                              hipStream_t stream) {
    // inputs: positions, hidden_states, Wqkv, Wo, q_gamma, k_gamma, cos, sin
    const float* hidden = (const float*)d_in[1];
    const float* Wqkv   = (const float*)d_in[2];
    const float* Wo     = (const float*)d_in[3];
    const float* qg     = (const float*)d_in[4];
    const float* kg     = (const float*)d_in[5];
    const float* cosb   = (const float*)d_in[6];
    const float* sinb   = (const float*)d_in[7];
    float* out = (float*)d_out;

    float* qkv  = (float*)d_ws;                         // 2048*6144 f32 = 50.3 MB
    float* attn = qkv + (size_t)S_LEN * QKV_DIM;        // 2048*4096 f32 = 33.6 MB

    // 1) qkv = hidden @ Wqkv   (fp16 MFMA, fp32 accumulate)
    gemm_f16_mfma<<<dim3(QKV_DIM / TN, S_LEN / TM), 256, 0, stream>>>(
        hidden, Wqkv, qkv, S_LEN, QKV_DIM, HIDDEN);

    // 2) RMSNorm + RoPE on q,k heads, in place
    rmsnorm_rope<<<dim3(NQ + NKV, S_LEN), 128, 0, stream>>>(qkv, qg, kg, cosb, sinb);

    // 3) causal GQA flash attention -> attn [s][h*HD+d]
    flash_attn<<<dim3(S_LEN / FBM, NQ), 256, 0, stream>>>(qkv, attn);

    // 4) out = attn @ Wo   (fp16 MFMA, fp32 accumulate)
    gemm_f16_mfma<<<dim3(HIDDEN / TN, S_LEN / TM), 256, 0, stream>>>(
        attn, Wo, out, S_LEN, HIDDEN, NQHD);
}

// Round 3
// 893.426 us; speedup vs baseline: 3.8219x; 2.1284x over previous
//
#include <hip/hip_runtime.h>
#include <hip/hip_bf16.h>

// Qwen3 attention block. Round 3: flash attention -> fp16 MFMA.
// B=1, S=2048, HIDDEN=4096, NQ=32, NKV=8 (GQA R=4), HD=128.
// Pipeline: gemm_f16_mfma(qkv) -> rmsnorm_rope (in-place) ->
//           flash_attn_mfma(fp16 MFMA) -> gemm_f16_mfma(out).

#define S_LEN   2048
#define HIDDEN  4096
#define NQ      32
#define NKV     8
#define HD      128
#define QKV_DIM 6144      // (NQ + 2*NKV) * HD
#define NQHD    4096      // NQ * HD
#define K_OFF   4096      // NQ*HD
#define V_OFF   5120      // (NQ+NKV)*HD
#define EPSF    1e-6f

typedef _Float16 half8 __attribute__((ext_vector_type(8)));
typedef _Float16 half4v __attribute__((ext_vector_type(4)));
typedef _Float16 half2v __attribute__((ext_vector_type(2)));
typedef float floatx4 __attribute__((ext_vector_type(4)));

// ---------------------------------------------------------------------------
// fp16 MFMA GEMM (unchanged from round 2): C[M,N] = A[M,K] @ B[K,N], fp32 I/O.
// ---------------------------------------------------------------------------
#define TM 128
#define TN 128
#define TK 32
#define LDH 40

__global__ __launch_bounds__(256) void gemm_f16_mfma(const float* __restrict__ A,
                                                     const float* __restrict__ B,
                                                     float* __restrict__ C,
                                                     int M, int N, int K) {
    __shared__ _Float16 As[TM][LDH];   // [m][k]
    __shared__ _Float16 Bs[TN][LDH];   // [n][k]

    const int tid = threadIdx.x;
    const int m0 = blockIdx.y * TM, n0 = blockIdx.x * TN;
    const int lane = tid & 63;
    const int wave = tid >> 6;
    const int wm = (wave >> 1) * 64, wn = (wave & 1) * 64;
    const int fl = lane & 15, quad = lane >> 4;

    const int ar = tid >> 3;            // 0..31
    const int ak = (tid & 7) * 4;       // 0,4,..,28
    const int bn = tid & 127;           // 0..127
    const int bk0 = (tid >> 7) * 4;     // 0 or 4

    floatx4 acc[4][4] = {};

    for (int k0 = 0; k0 < K; k0 += TK) {
        float4 av[4];
        #pragma unroll
        for (int l = 0; l < 4; ++l)
            av[l] = *(const float4*)(A + (size_t)(m0 + ar + l * 32) * K + k0 + ak);
        float bv[4][4];
        #pragma unroll
        for (int l = 0; l < 4; ++l) {
            const int kk = k0 + bk0 + l * 8;
            #pragma unroll
            for (int j = 0; j < 4; ++j)
                bv[l][j] = B[(size_t)(kk + j) * N + n0 + bn];
        }

        __syncthreads();

        #pragma unroll
        for (int l = 0; l < 4; ++l) {
            half4v h;
            h[0] = (_Float16)av[l].x; h[1] = (_Float16)av[l].y;
            h[2] = (_Float16)av[l].z; h[3] = (_Float16)av[l].w;
            *(half4v*)&As[ar + l * 32][ak] = h;
        }
        #pragma unroll
        for (int l = 0; l < 4; ++l) {
            half4v h;
            h[0] = (_Float16)bv[l][0]; h[1] = (_Float16)bv[l][1];
            h[2] = (_Float16)bv[l][2]; h[3] = (_Float16)bv[l][3];
            *(half4v*)&Bs[bn][bk0 + l * 8] = h;
        }

        __syncthreads();

        half8 af[4], bf[4];
        #pragma unroll
        for (int t = 0; t < 4; ++t) {
            af[t] = *(const half8*)&As[wm + t * 16 + fl][quad * 8];
            bf[t] = *(const half8*)&Bs[wn + t * 16 + fl][quad * 8];
        }
        #pragma unroll
        for (int i = 0; i < 4; ++i)
            #pragma unroll
            for (int j = 0; j < 4; ++j)
                acc[i][j] = __builtin_amdgcn_mfma_f32_16x16x32_f16(
                    af[i], bf[j], acc[i][j], 0, 0, 0);
    }

    #pragma unroll
    for (int i = 0; i < 4; ++i)
        #pragma unroll
        for (int j = 0; j < 4; ++j)
            #pragma unroll
            for (int r = 0; r < 4; ++r)
                C[(size_t)(m0 + wm + i * 16 + quad * 4 + r) * N
                  + n0 + wn + j * 16 + fl] = acc[i][j][r];
}

// ---------------------------------------------------------------------------
// Fused RMSNorm + RoPE, in-place on the qkv buffer. (unchanged)
// ---------------------------------------------------------------------------
__global__ __launch_bounds__(128) void rmsnorm_rope(float* __restrict__ qkv,
                                                    const float* __restrict__ qg,
                                                    const float* __restrict__ kg,
                                                    const float* __restrict__ cosb,
                                                    const float* __restrict__ sinb) {
    const int h = blockIdx.x;   // 0..39
    const int s = blockIdx.y;   // 0..2047
    const int d = threadIdx.x;  // 0..127
    const bool isq = (h < NQ);
    const int off = isq ? h * HD : K_OFF + (h - NQ) * HD;
    float* base = qkv + (size_t)s * QKV_DIM + off;

    float x = base[d];
    float ss = x * x;
    #pragma unroll
    for (int o = 32; o; o >>= 1) ss += __shfl_xor(ss, o);

    __shared__ float red[2];
    __shared__ float sh[HD];
    if ((d & 63) == 0) red[d >> 6] = ss;
    __syncthreads();
    float tot = red[0] + red[1];
    float rms = rsqrtf(tot * (1.0f / (float)HD) + EPSF);
    const float* gamma = isq ? qg : kg;
    float xn = x * rms * gamma[d];
    sh[d] = xn;
    __syncthreads();

    float out;
    if (d < 64) {
        float c = cosb[s * 64 + d], sn = sinb[s * 64 + d];
        out = xn * c - sh[d + 64] * sn;
    } else {
        int j = d - 64;
        float c = cosb[s * 64 + j], sn = sinb[s * 64 + j];
        out = xn * c + sh[d - 64] * sn;
    }
    base[d] = out;
}

// ---------------------------------------------------------------------------
// Flash attention, fp16 MFMA, online softmax in registers.
// Block = 256 threads = 4 waves; wave w owns query rows [m0+16w, m0+16w+16).
// Per KV tile (64 keys): stage K [n][d] + V transposed [d][j] in fp16,
// QK^T via 16 MFMAs/wave, register softmax (C-layout rows == quad*4+r,
// row-reductions via shfl_xor over the 16-lane fl group), P -> LDS (aliases
// Ks; A-layout), PV via 16 MFMAs/wave into 32-reg fp32 accumulator.
// LDS 52,224 B -> 3 blocks/CU.
// ---------------------------------------------------------------------------
#define FBM 64
#define FBN 64
#define LQK 136   // Qs/Ks row stride (fp16): 272 B, 16B-aligned b128 frags
#define LVP 68    // Vt/Ps row stride (fp16): 136 B, 8B-aligned b64 frags

__global__ __launch_bounds__(256, 3) void flash_attn_mfma(
        const float* __restrict__ qkv, float* __restrict__ attn) {
    __shared__ __align__(16) _Float16 Qs[FBM][LQK];
    __shared__ __align__(16) _Float16 KsPs[FBM][LQK];   // Ks; Ps aliases it
    __shared__ __align__(16) _Float16 Vt[HD][LVP];      // V transposed [d][j]
    _Float16 (*Ps)[LVP] = reinterpret_cast<_Float16 (*)[LVP]>(&KsPs[0][0]);

    const int tid = threadIdx.x;
    const int qt = blockIdx.x, h = blockIdx.y;
    const int kvh = h >> 2;
    const int m0 = qt * FBM;
    const int wave = tid >> 6, lane = tid & 63;
    const int fl = lane & 15, quad = lane >> 4;
    const float scale = 0.08838834764831845f;  // HD^-0.5

    // ---- stage Q tile (once): rows m0..m0+63, fp32 -> fp16, [m][d] ----
    {
        const int r = tid >> 5, c = tid & 31;   // +8 rows per pass
        #pragma unroll
        for (int l = 0; l < 8; ++l) {
            float4 q = *(const float4*)(qkv + (size_t)(m0 + r + 8 * l) * QKV_DIM
                                        + h * HD + 4 * c);
            half4v hh;
            hh[0] = (_Float16)q.x; hh[1] = (_Float16)q.y;
            hh[2] = (_Float16)q.z; hh[3] = (_Float16)q.w;
            *(half4v*)&Qs[r + 8 * l][4 * c] = hh;
        }
    }

    float m_prev[4], l_prev[4];
    #pragma unroll
    for (int r = 0; r < 4; ++r) { m_prev[r] = -1e30f; l_prev[r] = 0.f; }
    floatx4 oacc[8] = {};   // O[m=quad*4+r][d=dt*16+fl], dt=0..7

    for (int t = 0; t <= qt; ++t) {
        const int n0 = t * FBN;
        __syncthreads();   // (A) prev tile's Ps/Vt reads complete

        // ---- stage K tile: [j][d] row-major fp16 ----
        {
            const int j = tid >> 5, c = tid & 31;
            #pragma unroll
            for (int l = 0; l < 8; ++l) {
                float4 k = *(const float4*)(qkv + (size_t)(n0 + j + 8 * l) * QKV_DIM
                                            + K_OFF + kvh * HD + 4 * c);
                half4v hh;
                hh[0] = (_Float16)k.x; hh[1] = (_Float16)k.y;
                hh[2] = (_Float16)k.z; hh[3] = (_Float16)k.w;
                *(half4v*)&KsPs[j + 8 * l][4 * c] = hh;
            }
        }
        // ---- stage V tile transposed: Vt[d][j] ----
        {
            const int jp = tid & 7, c = tid >> 3;   // c in 0..31
            #pragma unroll
            for (int l = 0; l < 4; ++l) {
                const int p = jp + 8 * l;           // row-pair 0..31
                const float* v0p = qkv + (size_t)(n0 + 2 * p) * QKV_DIM
                                   + V_OFF + kvh * HD + 4 * c;
                float4 v0 = *(const float4*)v0p;
                float4 v1 = *(const float4*)(v0p + QKV_DIM);
                float a0[4] = {v0.x, v0.y, v0.z, v0.w};
                float a1[4] = {v1.x, v1.y, v1.z, v1.w};
                #pragma unroll
                for (int i = 0; i < 4; ++i) {
                    half2v hh;
                    hh[0] = (_Float16)a0[i]; hh[1] = (_Float16)a1[i];
                    *(half2v*)&Vt[4 * c + i][2 * p] = hh;
                }
            }
        }
        __syncthreads();   // (B) tiles staged (covers Q on first iter)

        // ---- QK^T: S[m][n], m = wave's 16 rows, n = 64 keys ----
        floatx4 sacc[4] = {};
        #pragma unroll
        for (int ks = 0; ks < 4; ++ks) {
            half8 af = *(const half8*)&Qs[wave * 16 + fl][ks * 32 + quad * 8];
            #pragma unroll
            for (int nt = 0; nt < 4; ++nt) {
                half8 bf = *(const half8*)&KsPs[nt * 16 + fl][ks * 32 + quad * 8];
                sacc[nt] = __builtin_amdgcn_mfma_f32_16x16x32_f16(af, bf, sacc[nt], 0, 0, 0);
            }
        }
        __syncthreads();   // (C) all Ks reads done before Ps (alias) writes

        // ---- online softmax, rows m = quad*4+r (held by this lane) ----
        const bool diag = (t == qt);
        float mx[4] = {-1e30f, -1e30f, -1e30f, -1e30f};
        #pragma unroll
        for (int nt = 0; nt < 4; ++nt) {
            #pragma unroll
            for (int r = 0; r < 4; ++r) {
                float s = sacc[nt][r] * scale;
                if (diag && (n0 + nt * 16 + fl > m0 + wave * 16 + quad * 4 + r))
                    s = -1e30f;
                sacc[nt][r] = s;
                mx[r] = fmaxf(mx[r], s);
            }
        }
        #pragma unroll
        for (int r = 0; r < 4; ++r) {
            #pragma unroll
            for (int o = 8; o; o >>= 1) mx[r] = fmaxf(mx[r], __shfl_xor(mx[r], o));
        }
        float alpha[4], rs[4];
        #pragma unroll
        for (int r = 0; r < 4; ++r) {
            float nm = fmaxf(m_prev[r], mx[r]);
            alpha[r] = __expf(m_prev[r] - nm);
            m_prev[r] = nm;
            rs[r] = 0.f;
        }
        #pragma unroll
        for (int nt = 0; nt < 4; ++nt) {
            #pragma unroll
            for (int r = 0; r < 4; ++r) {
                float p = __expf(sacc[nt][r] - m_prev[r]);
                rs[r] += p;
                Ps[wave * 16 + quad * 4 + r][nt * 16 + fl] = (_Float16)p;
            }
        }
        #pragma unroll
        for (int r = 0; r < 4; ++r) {
            #pragma unroll
            for (int o = 8; o; o >>= 1) rs[r] += __shfl_xor(rs[r], o);
            l_prev[r] = l_prev[r] * alpha[r] + rs[r];
        }
        // rescale O accumulator (same lanes hold matching rows)
        #pragma unroll
        for (int dt = 0; dt < 8; ++dt)
            #pragma unroll
            for (int r = 0; r < 4; ++r) oacc[dt][r] *= alpha[r];

        // ---- PV: O += P[16x64] @ V[64x128]; same-wave Ps (no barrier) ----
        #pragma unroll
        for (int ks2 = 0; ks2 < 2; ++ks2) {
            half4v plo = *(const half4v*)&Ps[wave * 16 + fl][ks2 * 32 + quad * 8];
            half4v phi = *(const half4v*)&Ps[wave * 16 + fl][ks2 * 32 + quad * 8 + 4];
            half8 pa = __builtin_shufflevector(plo, phi, 0, 1, 2, 3, 4, 5, 6, 7);
            #pragma unroll
            for (int dt = 0; dt < 8; ++dt) {
                half4v vlo = *(const half4v*)&Vt[dt * 16 + fl][ks2 * 32 + quad * 8];
                half4v vhi = *(const half4v*)&Vt[dt * 16 + fl][ks2 * 32 + quad * 8 + 4];
                half8 vb = __builtin_shufflevector(vlo, vhi, 0, 1, 2, 3, 4, 5, 6, 7);
                oacc[dt] = __builtin_amdgcn_mfma_f32_16x16x32_f16(pa, vb, oacc[dt], 0, 0, 0);
            }
        }
    }

    // ---- epilogue: normalize and store ----
    float linv[4];
    #pragma unroll
    for (int r = 0; r < 4; ++r) linv[r] = 1.0f / l_prev[r];
    #pragma unroll
    for (int dt = 0; dt < 8; ++dt)
        #pragma unroll
        for (int r = 0; r < 4; ++r)
            attn[(size_t)(m0 + wave * 16 + quad * 4 + r) * NQHD
                 + h * HD + dt * 16 + fl] = oacc[dt][r] * linv[r];
}

// ---------------------------------------------------------------------------
extern "C" void kernel_launch(void* const* d_in, const int* in_sizes, int n_in,
                              void* d_out, int out_size, void* d_ws, size_t ws_size,
                              hipStream_t stream) {
    // inputs: positions, hidden_states, Wqkv, Wo, q_gamma, k_gamma, cos, sin
    const float* hidden = (const float*)d_in[1];
    const float* Wqkv   = (const float*)d_in[2];
    const float* Wo     = (const float*)d_in[3];
    const float* qg     = (const float*)d_in[4];
    const float* kg     = (const float*)d_in[5];
    const float* cosb   = (const float*)d_in[6];
    const float* sinb   = (const float*)d_in[7];
    float* out = (float*)d_out;

    float* qkv  = (float*)d_ws;                         // 50.3 MB
    float* attn = qkv + (size_t)S_LEN * QKV_DIM;        // 33.6 MB

    gemm_f16_mfma<<<dim3(QKV_DIM / TN, S_LEN / TM), 256, 0, stream>>>(
        hidden, Wqkv, qkv, S_LEN, QKV_DIM, HIDDEN);

    rmsnorm_rope<<<dim3(NQ + NKV, S_LEN), 128, 0, stream>>>(qkv, qg, kg, cosb, sinb);

    flash_attn_mfma<<<dim3(S_LEN / FBM, NQ), 256, 0, stream>>>(qkv, attn);

    gemm_f16_mfma<<<dim3(HIDDEN / TN, S_LEN / TM), 256, 0, stream>>>(
        attn, Wo, out, S_LEN, HIDDEN, NQHD);
}

// Round 4
// 689.560 us; speedup vs baseline: 4.9519x; 1.2956x over previous
//
#include <hip/hip_runtime.h>
#include <hip/hip_bf16.h>

// Qwen3 attention block. Round 4: m97-style fp16 GEMMs with global_load_lds,
// fp16 intermediate pipeline (weights pre-transposed+converted; qkv16 scratch
// lives inside d_out and is dead before the final GEMM overwrites it).
// B=1, S=2048, HIDDEN=4096, NQ=32, NKV=8 (GQA R=4), HD=128.

#define S_LEN   2048
#define HIDDEN  4096
#define NQ      32
#define NKV     8
#define HD      128
#define QKV_DIM 6144      // (NQ + 2*NKV) * HD
#define NQHD    4096      // NQ * HD
#define K_OFF   4096
#define V_OFF   5120
#define EPSF    1e-6f

typedef _Float16 half8 __attribute__((ext_vector_type(8)));
typedef _Float16 half4v __attribute__((ext_vector_type(4)));
typedef _Float16 half2v __attribute__((ext_vector_type(2)));
typedef float floatx4 __attribute__((ext_vector_type(4)));

__device__ __forceinline__ void gload_lds16(const void* g, void* l) {
    __builtin_amdgcn_global_load_lds(
        (const __attribute__((address_space(1))) unsigned int*)g,
        (__attribute__((address_space(3))) unsigned int*)l, 16, 0, 0);
}

// ---------------------------------------------------------------------------
// fp32 -> fp16 elementwise convert (8 elems/thread)
// ---------------------------------------------------------------------------
__global__ __launch_bounds__(256) void conv_f32_f16(const float* __restrict__ src,
                                                    _Float16* __restrict__ dst) {
    const size_t i = ((size_t)blockIdx.x * 256 + threadIdx.x) * 8;
    float4 a = *(const float4*)(src + i);
    float4 b = *(const float4*)(src + i + 4);
    half8 h;
    h[0] = (_Float16)a.x; h[1] = (_Float16)a.y; h[2] = (_Float16)a.z; h[3] = (_Float16)a.w;
    h[4] = (_Float16)b.x; h[5] = (_Float16)b.y; h[6] = (_Float16)b.z; h[7] = (_Float16)b.w;
    *(half8*)(dst + i) = h;
}

// ---------------------------------------------------------------------------
// W[K][N] fp32 -> Wt[N][K] fp16 (transpose + convert), 64x64 tiles via LDS.
// ---------------------------------------------------------------------------
__global__ __launch_bounds__(256) void conv_w_transpose(const float* __restrict__ src,
                                                        _Float16* __restrict__ dst,
                                                        int N, int K) {
    __shared__ float T[64][65];
    const int tid = threadIdx.x;
    const int n0 = blockIdx.x * 64, k0 = blockIdx.y * 64;
    const int rr = tid >> 4, cc = (tid & 15) * 4;
    #pragma unroll
    for (int l = 0; l < 4; ++l) {
        const int r = rr + l * 16;
        *(float4*)&T[r][cc] = *(const float4*)(src + (size_t)(k0 + r) * N + n0 + cc);
    }
    __syncthreads();
    #pragma unroll
    for (int l = 0; l < 4; ++l) {
        const int rn = rr + l * 16;
        half4v h;
        h[0] = (_Float16)T[cc + 0][rn];
        h[1] = (_Float16)T[cc + 1][rn];
        h[2] = (_Float16)T[cc + 2][rn];
        h[3] = (_Float16)T[cc + 3][rn];
        *(half4v*)(dst + (size_t)(n0 + rn) * K + k0 + cc) = h;
    }
}

// ---------------------------------------------------------------------------
// m97-style fp16 GEMM: C[M][ldc] = A[M][K] @ Bt[N][K]^T.
// 128x128 tile, BK=32, 4 waves 2x2 (64x64 each, 4x4 MFMA 16x16x32).
// Staging: 4x global_load_lds width=16 per thread per K-iter into unpadded
// [row][32]-half LDS (layout mandated by the wave-uniform-base + lane*16 rule).
// ---------------------------------------------------------------------------
template <typename CT>
__global__ __launch_bounds__(256) void gemm_bt_f16(const _Float16* __restrict__ A,
                                                   const _Float16* __restrict__ Bt,
                                                   CT* __restrict__ C,
                                                   int K, int ldc) {
    __shared__ _Float16 As[128 * 32];
    __shared__ _Float16 Bs[128 * 32];

    const int tid = threadIdx.x;
    const int m0 = blockIdx.y * 128, n0 = blockIdx.x * 128;
    const int wave = tid >> 6, lane = tid & 63;
    const int fl = lane & 15, quad = lane >> 4;
    const int wm = (wave >> 1) * 64, wn = (wave & 1) * 64;

    // staging geometry: chunk = wave*2+i covers 16 rows; lane -> row lane/4,
    // k-group (lane&3)*8 halves (16 B). LDS dest = chunk base + lane*16.
    const int srow = lane >> 2;
    const int skoff = (lane & 3) * 8;

    floatx4 acc[4][4] = {};

    for (int k0 = 0; k0 < K; k0 += 32) {
        __syncthreads();   // previous iteration's fragment reads done
        #pragma unroll
        for (int i = 0; i < 2; ++i) {
            const int chunk = wave * 2 + i;
            const int row = chunk * 16 + srow;
            gload_lds16(A + (size_t)(m0 + row) * K + k0 + skoff, &As[chunk * 512]);
            gload_lds16(Bt + (size_t)(n0 + row) * K + k0 + skoff, &Bs[chunk * 512]);
        }
        __syncthreads();   // staging drained (vmcnt(0) before barrier)

        half8 af[4], bf[4];
        #pragma unroll
        for (int t = 0; t < 4; ++t) {
            af[t] = *(const half8*)&As[(wm + t * 16 + fl) * 32 + quad * 8];
            bf[t] = *(const half8*)&Bs[(wn + t * 16 + fl) * 32 + quad * 8];
        }
        #pragma unroll
        for (int i = 0; i < 4; ++i)
            #pragma unroll
            for (int j = 0; j < 4; ++j)
                acc[i][j] = __builtin_amdgcn_mfma_f32_16x16x32_f16(
                    af[i], bf[j], acc[i][j], 0, 0, 0);
    }

    #pragma unroll
    for (int i = 0; i < 4; ++i)
        #pragma unroll
        for (int j = 0; j < 4; ++j)
            #pragma unroll
            for (int r = 0; r < 4; ++r)
                C[(size_t)(m0 + wm + i * 16 + quad * 4 + r) * ldc
                  + n0 + wn + j * 16 + fl] = (CT)acc[i][j][r];
}

// ---------------------------------------------------------------------------
// Fused RMSNorm + RoPE, in-place on fp16 qkv (fp32 math).
// ---------------------------------------------------------------------------
__global__ __launch_bounds__(128) void rmsnorm_rope16(_Float16* __restrict__ qkv,
                                                      const float* __restrict__ qg,
                                                      const float* __restrict__ kg,
                                                      const float* __restrict__ cosb,
                                                      const float* __restrict__ sinb) {
    const int h = blockIdx.x;   // 0..39
    const int s = blockIdx.y;   // 0..2047
    const int d = threadIdx.x;  // 0..127
    const bool isq = (h < NQ);
    const int off = isq ? h * HD : K_OFF + (h - NQ) * HD;
    _Float16* base = qkv + (size_t)s * QKV_DIM + off;

    float x = (float)base[d];
    float ss = x * x;
    #pragma unroll
    for (int o = 32; o; o >>= 1) ss += __shfl_xor(ss, o);

    __shared__ float red[2];
    __shared__ float sh[HD];
    if ((d & 63) == 0) red[d >> 6] = ss;
    __syncthreads();
    float tot = red[0] + red[1];
    float rms = rsqrtf(tot * (1.0f / (float)HD) + EPSF);
    const float* gamma = isq ? qg : kg;
    float xn = x * rms * gamma[d];
    sh[d] = xn;
    __syncthreads();

    float out;
    if (d < 64) {
        float c = cosb[s * 64 + d], sn = sinb[s * 64 + d];
        out = xn * c - sh[d + 64] * sn;
    } else {
        int j = d - 64;
        float c = cosb[s * 64 + j], sn = sinb[s * 64 + j];
        out = xn * c + sh[d - 64] * sn;
    }
    base[d] = (_Float16)out;
}

// ---------------------------------------------------------------------------
// Flash attention, fp16 MFMA, fp16 input (qkv16) and fp16 output (attn16).
// Same verified structure as round 3, minus all fp32->fp16 conversions.
// ---------------------------------------------------------------------------
#define FBM 64
#define FBN 64
#define LQK 136
#define LVP 68

__global__ __launch_bounds__(256, 3) void flash_attn_mfma(
        const _Float16* __restrict__ qkv, _Float16* __restrict__ attn) {
    __shared__ __align__(16) _Float16 Qs[FBM][LQK];
    __shared__ __align__(16) _Float16 KsPs[FBM][LQK];   // Ks; Ps aliases it
    __shared__ __align__(16) _Float16 Vt[HD][LVP];      // V transposed [d][j]
    _Float16 (*Ps)[LVP] = reinterpret_cast<_Float16 (*)[LVP]>(&KsPs[0][0]);

    const int tid = threadIdx.x;
    const int qt = blockIdx.x, h = blockIdx.y;
    const int kvh = h >> 2;
    const int m0 = qt * FBM;
    const int wave = tid >> 6, lane = tid & 63;
    const int fl = lane & 15, quad = lane >> 4;
    const float scale = 0.08838834764831845f;  // HD^-0.5

    // ---- stage Q tile once: 64 rows x 128 halves ----
    #pragma unroll
    for (int l = 0; l < 4; ++l) {
        const int f = tid + l * 256;
        const int r = f >> 4, c8 = (f & 15) * 8;
        *(half8*)&Qs[r][c8] =
            *(const half8*)(qkv + (size_t)(m0 + r) * QKV_DIM + h * HD + c8);
    }

    float m_prev[4], l_prev[4];
    #pragma unroll
    for (int r = 0; r < 4; ++r) { m_prev[r] = -1e30f; l_prev[r] = 0.f; }
    floatx4 oacc[8] = {};

    for (int t = 0; t <= qt; ++t) {
        const int n0 = t * FBN;
        __syncthreads();   // (A) prev tile's Ps/Vt reads complete

        // K tile [j][d]
        #pragma unroll
        for (int l = 0; l < 4; ++l) {
            const int f = tid + l * 256;
            const int r = f >> 4, c8 = (f & 15) * 8;
            *(half8*)&KsPs[r][c8] =
                *(const half8*)(qkv + (size_t)(n0 + r) * QKV_DIM + K_OFF + kvh * HD + c8);
        }
        // V tile transposed Vt[d][j]
        {
            const int p = tid & 31, g0 = tid >> 5;   // rows 2p,2p+1; d-group
            #pragma unroll
            for (int gi = 0; gi < 2; ++gi) {
                const int g = g0 + gi * 8;           // 0..15 -> d = 8g
                const _Float16* v0p = qkv + (size_t)(n0 + 2 * p) * QKV_DIM
                                      + V_OFF + kvh * HD + 8 * g;
                half8 va = *(const half8*)v0p;
                half8 vb = *(const half8*)(v0p + QKV_DIM);
                #pragma unroll
                for (int i = 0; i < 8; ++i) {
                    half2v hh; hh[0] = va[i]; hh[1] = vb[i];
                    *(half2v*)&Vt[8 * g + i][2 * p] = hh;
                }
            }
        }
        __syncthreads();   // (B) tiles staged

        // QK^T
        floatx4 sacc[4] = {};
        #pragma unroll
        for (int ks = 0; ks < 4; ++ks) {
            half8 af = *(const half8*)&Qs[wave * 16 + fl][ks * 32 + quad * 8];
            #pragma unroll
            for (int nt = 0; nt < 4; ++nt) {
                half8 bf = *(const half8*)&KsPs[nt * 16 + fl][ks * 32 + quad * 8];
                sacc[nt] = __builtin_amdgcn_mfma_f32_16x16x32_f16(af, bf, sacc[nt], 0, 0, 0);
            }
        }
        __syncthreads();   // (C) Ks reads done before Ps writes (alias)

        // online softmax (rows m = quad*4+r in-lane)
        const bool diag = (t == qt);
        float mx[4] = {-1e30f, -1e30f, -1e30f, -1e30f};
        #pragma unroll
        for (int nt = 0; nt < 4; ++nt)
            #pragma unroll
            for (int r = 0; r < 4; ++r) {
                float s = sacc[nt][r] * scale;
                if (diag && (n0 + nt * 16 + fl > m0 + wave * 16 + quad * 4 + r))
                    s = -1e30f;
                sacc[nt][r] = s;
                mx[r] = fmaxf(mx[r], s);
            }
        #pragma unroll
        for (int r = 0; r < 4; ++r)
            #pragma unroll
            for (int o = 8; o; o >>= 1) mx[r] = fmaxf(mx[r], __shfl_xor(mx[r], o));
        float alpha[4], rs[4];
        #pragma unroll
        for (int r = 0; r < 4; ++r) {
            float nm = fmaxf(m_prev[r], mx[r]);
            alpha[r] = __expf(m_prev[r] - nm);
            m_prev[r] = nm;
            rs[r] = 0.f;
        }
        #pragma unroll
        for (int nt = 0; nt < 4; ++nt)
            #pragma unroll
            for (int r = 0; r < 4; ++r) {
                float p = __expf(sacc[nt][r] - m_prev[r]);
                rs[r] += p;
                Ps[wave * 16 + quad * 4 + r][nt * 16 + fl] = (_Float16)p;
            }
        #pragma unroll
        for (int r = 0; r < 4; ++r) {
            #pragma unroll
            for (int o = 8; o; o >>= 1) rs[r] += __shfl_xor(rs[r], o);
            l_prev[r] = l_prev[r] * alpha[r] + rs[r];
        }
        #pragma unroll
        for (int dt = 0; dt < 8; ++dt)
            #pragma unroll
            for (int r = 0; r < 4; ++r) oacc[dt][r] *= alpha[r];

        // PV (same-wave Ps, no barrier needed before reads)
        #pragma unroll
        for (int ks2 = 0; ks2 < 2; ++ks2) {
            half4v plo = *(const half4v*)&Ps[wave * 16 + fl][ks2 * 32 + quad * 8];
            half4v phi = *(const half4v*)&Ps[wave * 16 + fl][ks2 * 32 + quad * 8 + 4];
            half8 pa = __builtin_shufflevector(plo, phi, 0, 1, 2, 3, 4, 5, 6, 7);
            #pragma unroll
            for (int dt = 0; dt < 8; ++dt) {
                half4v vlo = *(const half4v*)&Vt[dt * 16 + fl][ks2 * 32 + quad * 8];
                half4v vhi = *(const half4v*)&Vt[dt * 16 + fl][ks2 * 32 + quad * 8 + 4];
                half8 vb = __builtin_shufflevector(vlo, vhi, 0, 1, 2, 3, 4, 5, 6, 7);
                oacc[dt] = __builtin_amdgcn_mfma_f32_16x16x32_f16(pa, vb, oacc[dt], 0, 0, 0);
            }
        }
    }

    float linv[4];
    #pragma unroll
    for (int r = 0; r < 4; ++r) linv[r] = 1.0f / l_prev[r];
    #pragma unroll
    for (int dt = 0; dt < 8; ++dt)
        #pragma unroll
        for (int r = 0; r < 4; ++r)
            attn[(size_t)(m0 + wave * 16 + quad * 4 + r) * NQHD
                 + h * HD + dt * 16 + fl] = (_Float16)(oacc[dt][r] * linv[r]);
}

// ---------------------------------------------------------------------------
extern "C" void kernel_launch(void* const* d_in, const int* in_sizes, int n_in,
                              void* d_out, int out_size, void* d_ws, size_t ws_size,
                              hipStream_t stream) {
    // inputs: positions, hidden_states, Wqkv, Wo, q_gamma, k_gamma, cos, sin
    const float* hidden = (const float*)d_in[1];
    const float* Wqkv   = (const float*)d_in[2];
    const float* Wo     = (const float*)d_in[3];
    const float* qg     = (const float*)d_in[4];
    const float* kg     = (const float*)d_in[5];
    const float* cosb   = (const float*)d_in[6];
    const float* sinb   = (const float*)d_in[7];
    float* out = (float*)d_out;

    // ws layout (67.1 MB total):
    //   buf0: h16 [2048][4096]     -> later attn16 [2048][4096] (same size)
    //   buf1: wT  [6144][4096]     -> later woT [4096][4096] (smaller)
    // qkv16 [2048][6144] fp16 lives in d_out (25.2 MB of its 33.6 MB);
    // dead before gemm2 overwrites d_out with the final fp32 output.
    _Float16* buf0  = (_Float16*)d_ws;
    _Float16* wT    = buf0 + (size_t)S_LEN * HIDDEN;
    _Float16* qkv16 = (_Float16*)d_out;
    _Float16* attn16 = buf0;

    // 1) convert hidden -> fp16
    conv_f32_f16<<<(S_LEN * HIDDEN) / 2048, 256, 0, stream>>>(hidden, buf0);
    // 2) Wqkv [K=4096][N=6144] -> wT [6144][4096] fp16
    conv_w_transpose<<<dim3(QKV_DIM / 64, HIDDEN / 64), 256, 0, stream>>>(
        Wqkv, wT, QKV_DIM, HIDDEN);
    // 3) qkv16 = h16 @ wT^T
    gemm_bt_f16<_Float16><<<dim3(QKV_DIM / 128, S_LEN / 128), 256, 0, stream>>>(
        buf0, wT, qkv16, HIDDEN, QKV_DIM);
    // 4) RMSNorm + RoPE in place (fp16)
    rmsnorm_rope16<<<dim3(NQ + NKV, S_LEN), 128, 0, stream>>>(qkv16, qg, kg, cosb, sinb);
    // 5) flash attention -> attn16 (buf0; h16 dead)
    flash_attn_mfma<<<dim3(S_LEN / FBM, NQ), 256, 0, stream>>>(qkv16, attn16);
    // 6) Wo [4096][4096] -> woT fp16 (reuses wT slot; Wqkv16 dead)
    conv_w_transpose<<<dim3(HIDDEN / 64, NQHD / 64), 256, 0, stream>>>(
        Wo, wT, HIDDEN, NQHD);
    // 7) out = attn16 @ woT^T (fp32 store; overwrites qkv16 scratch)
    gemm_bt_f16<float><<<dim3(HIDDEN / 128, S_LEN / 128), 256, 0, stream>>>(
        attn16, wT, out, NQHD, HIDDEN);
}